// Round 4
// baseline (379.934 us; speedup 1.0000x reference)
//
#include <hip/hip_runtime.h>

// VEConv: E=800000, N=50000, RBF=100, D=64.
// Round 4: two-phase CSR segment-sum to eliminate the 51.2M device-scope f32
// atomicAdds (round-3 bottleneck theory: atomic backpressure at the coherence
// point serialized the whole memory system).
//   build:  hist(dst) -> 2-level exclusive scan -> offs/cursor
//   phaseA: round-3 GEMM body; epilogue claims CSR slot (int atomic, 1/edge)
//           and stores the bf16 message row to msg[slot][64] (plain stores)
//   phaseB: 1 wave per node, sums its contiguous msg rows -> out
// Fallback to the round-3 atomic epilogue if ws_size is too small.
#define RBF_DIM 100

typedef __attribute__((ext_vector_type(8))) short bf16x8;
typedef __attribute__((ext_vector_type(4))) float f32x4;

__device__ __forceinline__ unsigned short f2bf(float f) {
    union { float f; unsigned int u; } v; v.f = f;
    unsigned int r = (v.u + 0x7FFFu + ((v.u >> 16) & 1u)) >> 16;
    return (unsigned short)r;
}
__device__ __forceinline__ float bf2f(unsigned short u) {
    union { unsigned int u; float f; } v; v.u = ((unsigned int)u) << 16;
    return v.f;
}
__device__ __forceinline__ bf16x8 cvt8(f32x4 a, f32x4 b) {
    bf16x8 r;
    r[0] = (short)f2bf(a[0]); r[1] = (short)f2bf(a[1]);
    r[2] = (short)f2bf(a[2]); r[3] = (short)f2bf(a[3]);
    r[4] = (short)f2bf(b[0]); r[5] = (short)f2bf(b[1]);
    r[6] = (short)f2bf(b[2]); r[7] = (short)f2bf(b[3]);
    return r;
}

// ---- weights: transposed bf16 into ws[0..32768) ----
__global__ void prep_weights(const float* __restrict__ W1, const float* __restrict__ b1,
                             const float* __restrict__ W2, const float* __restrict__ W3,
                             unsigned short* __restrict__ ws) {
    int t = threadIdx.x;
    for (int idx = t; idx < 64 * 128; idx += 256) {
        int o = idx >> 7, k = idx & 127;
        float v = (k < RBF_DIM) ? W1[k * 64 + o] : ((k == RBF_DIM) ? b1[o] : 0.0f);
        ws[idx] = f2bf(v);
    }
    for (int idx = t; idx < 64 * 64; idx += 256) {
        int o = idx >> 6, k = idx & 63;
        ws[8192 + idx]  = f2bf(W2[k * 64 + o]);
        ws[12288 + idx] = f2bf(W3[k * 64 + o]);
    }
}

// ---- CSR build ----
__global__ void k_hist(const int* __restrict__ dst, int* __restrict__ counts, int E) {
    int i = blockIdx.x * 256 + threadIdx.x;
    if (i < E) atomicAdd(&counts[dst[i]], 1);
}

__global__ void k_bsum(const int* __restrict__ counts, int* __restrict__ bsum, int N) {
    __shared__ int red[4];
    int i = blockIdx.x * 256 + threadIdx.x;
    int v = (i < N) ? counts[i] : 0;
    for (int off = 32; off; off >>= 1) v += __shfl_down(v, off, 64);
    int lane = threadIdx.x & 63, w = threadIdx.x >> 6;
    if (lane == 0) red[w] = v;
    __syncthreads();
    if (threadIdx.x == 0) bsum[blockIdx.x] = red[0] + red[1] + red[2] + red[3];
}

__global__ void k_scan_bsum(int* __restrict__ bsum, int* __restrict__ offs,
                            int NB, int N, int E) {
    __shared__ int s[256];
    int t = threadIdx.x;
    int v = (t < NB) ? bsum[t] : 0;
    s[t] = v;
    __syncthreads();
    for (int off = 1; off < 256; off <<= 1) {
        int x = (t >= off) ? s[t - off] : 0;
        __syncthreads();
        s[t] += x;
        __syncthreads();
    }
    if (t < NB) bsum[t] = s[t] - v;   // exclusive
    if (t == 0) offs[N] = E;
}

__global__ void k_scan_final(const int* __restrict__ counts, const int* __restrict__ bsum,
                             int* __restrict__ offs, int* __restrict__ cursor, int N) {
    __shared__ int s[256];
    int t = threadIdx.x, i = blockIdx.x * 256 + t;
    int v = (i < N) ? counts[i] : 0;
    s[t] = v;
    __syncthreads();
    for (int off = 1; off < 256; off <<= 1) {
        int x = (t >= off) ? s[t - off] : 0;
        __syncthreads();
        s[t] += x;
        __syncthreads();
    }
    if (i < N) {
        int excl = s[t] - v + bsum[blockIdx.x];
        offs[i] = excl;
        cursor[i] = excl;
    }
}

// ---- phase A: 64 edges/block, 4 independent waves x 16 edges ----
template <bool CSR>
__global__ __launch_bounds__(256, 4)
void veconv_main(const float* __restrict__ rbf, const float* __restrict__ edge_f,
                 const float* __restrict__ node,
                 const float* __restrict__ b2, const float* __restrict__ b3,
                 const int* __restrict__ src, const int* __restrict__ dst,
                 const unsigned short* __restrict__ wsw,
                 float* __restrict__ out,
                 unsigned short* __restrict__ msg, int* __restrict__ cursor) {
    __shared__ unsigned short sp_lds[4 * 16 * 64];

    const int tid = threadIdx.x;
    const int lane = tid & 63, wid = tid >> 6;
    const int l15 = lane & 15, g = lane >> 4;
    const int ew0 = blockIdx.x * 64 + wid * 16;
    const int eg = ew0 + l15;
    const int swz = (l15 & 7) << 3;

    // epilogue indices (edge e_loc = 4g + r); hoist node gathers to hide latency
    int srcv[4], dstv[4];
    for (int r = 0; r < 4; ++r) {
        srcv[r] = src[ew0 + 4 * g + r];
        dstv[r] = dst[ew0 + 4 * g + r];
    }
    float nd[4][4];
    for (int r = 0; r < 4; ++r)
        for (int t4 = 0; t4 < 4; ++t4)
            nd[r][t4] = node[(long)srcv[r] * 64 + 16 * t4 + l15];
    float b2v[4], b3v[4];
    for (int t4 = 0; t4 < 4; ++t4) { b2v[t4] = b2[16 * t4 + l15]; b3v[t4] = b3[16 * t4 + l15]; }

    // ---- GEMM1: D1[d][e] = W1T @ rbf^T ----
    const float* rrow = rbf + (long)eg * RBF_DIM;
    f32x4 acc1[4];
    for (int t4 = 0; t4 < 4; ++t4) acc1[t4] = (f32x4){0.f, 0.f, 0.f, 0.f};
    for (int ks = 0; ks < 3; ++ks) {
        f32x4 a = *(const f32x4*)(rrow + 32 * ks + 8 * g);
        f32x4 b = *(const f32x4*)(rrow + 32 * ks + 8 * g + 4);
        bf16x8 bf = cvt8(a, b);
        for (int t4 = 0; t4 < 4; ++t4) {
            bf16x8 w = *(const bf16x8*)(wsw + (16 * t4 + l15) * 128 + 32 * ks + 8 * g);
            acc1[t4] = __builtin_amdgcn_mfma_f32_16x16x32_bf16(w, bf, acc1[t4], 0, 0, 0);
        }
    }
    {   // ks=3: k=96..99 real (g==0), k=100 = bias-1.0 col
        bf16x8 bf = (bf16x8){0, 0, 0, 0, 0, 0, 0, 0};
        if (g == 0) {
            f32x4 a = *(const f32x4*)(rrow + 96);
            bf[0] = (short)f2bf(a[0]); bf[1] = (short)f2bf(a[1]);
            bf[2] = (short)f2bf(a[2]); bf[3] = (short)f2bf(a[3]);
            bf[4] = (short)0x3F80;
        }
        for (int t4 = 0; t4 < 4; ++t4) {
            bf16x8 w = *(const bf16x8*)(wsw + (16 * t4 + l15) * 128 + 96 + 8 * g);
            acc1[t4] = __builtin_amdgcn_mfma_f32_16x16x32_bf16(w, bf, acc1[t4], 0, 0, 0);
        }
    }

    // ---- softplus -> sp_lds (intra-wave region only, no barrier) ----
    for (int t4 = 0; t4 < 4; ++t4) {
        float spv[4];
        for (int r = 0; r < 4; ++r) {
            float x = acc1[t4][r];
            float bx = 0.5f * x;
            float s = 2.0f * __logf(1.0f + __expf(bx));
            spv[r] = (bx > 14.0f) ? x : s;
        }
        unsigned int p0 = (unsigned int)f2bf(spv[0]) | ((unsigned int)f2bf(spv[1]) << 16);
        unsigned int p1 = (unsigned int)f2bf(spv[2]) | ((unsigned int)f2bf(spv[3]) << 16);
        int el = (wid * 16 + l15) * 64 + ((16 * t4 + 4 * g) ^ swz);
        *(uint2*)&sp_lds[el] = make_uint2(p0, p1);
    }

    // ---- GEMM2/3 swapped: D[e][d] ----
    const float* erow = edge_f + (long)eg * 64;
    f32x4 acc2[4], acc3[4];
    for (int t4 = 0; t4 < 4; ++t4) {
        acc2[t4] = (f32x4){0.f, 0.f, 0.f, 0.f};
        acc3[t4] = (f32x4){0.f, 0.f, 0.f, 0.f};
    }
    for (int ks = 0; ks < 2; ++ks) {
        bf16x8 asp = *(const bf16x8*)&sp_lds[(wid * 16 + l15) * 64 + ((32 * ks + 8 * g) ^ swz)];
        f32x4 a = *(const f32x4*)(erow + 32 * ks + 8 * g);
        f32x4 b = *(const f32x4*)(erow + 32 * ks + 8 * g + 4);
        bf16x8 aef = cvt8(a, b);
        for (int t4 = 0; t4 < 4; ++t4) {
            bf16x8 w2 = *(const bf16x8*)(wsw + 8192  + (16 * t4 + l15) * 64 + 32 * ks + 8 * g);
            bf16x8 w3 = *(const bf16x8*)(wsw + 12288 + (16 * t4 + l15) * 64 + 32 * ks + 8 * g);
            acc2[t4] = __builtin_amdgcn_mfma_f32_16x16x32_bf16(asp, w2, acc2[t4], 0, 0, 0);
            acc3[t4] = __builtin_amdgcn_mfma_f32_16x16x32_bf16(aef, w3, acc3[t4], 0, 0, 0);
        }
    }
    // acc2/acc3: lane (g,l15) holds edge 4g+r, dim 16*t4+l15

    if constexpr (CSR) {
        // claim slots (one int atomic per edge, on l15==0 lanes), broadcast in-group
        int slot[4];
        for (int r = 0; r < 4; ++r) {
            int sl = 0;
            if (l15 == 0) sl = atomicAdd(&cursor[dstv[r]], 1);
            slot[r] = __shfl(sl, lane & 48, 64);
        }
        for (int r = 0; r < 4; ++r) {
            unsigned short* mrow = msg + (long)slot[r] * 64;
            for (int t4 = 0; t4 < 4; ++t4) {
                float v = nd[r][t4] * (acc2[t4][r] + b2v[t4]) + (acc3[t4][r] + b3v[t4]);
                mrow[16 * t4 + l15] = f2bf(v);
            }
        }
    } else {
        for (int r = 0; r < 4; ++r) {
            float* orow = out + (long)dstv[r] * 64 + l15;
            for (int t4 = 0; t4 < 4; ++t4) {
                float v = nd[r][t4] * (acc2[t4][r] + b2v[t4]) + (acc3[t4][r] + b3v[t4]);
                atomicAdd(&orow[16 * t4], v);
            }
        }
    }
}

// ---- phase B: 1 wave per node, lane = dim ----
__global__ __launch_bounds__(256)
void k_segsum(const unsigned short* __restrict__ msg, const int* __restrict__ offs,
              float* __restrict__ out, int N) {
    int wid = threadIdx.x >> 6, lane = threadIdx.x & 63;
    int n = blockIdx.x * 4 + wid;
    if (n >= N) return;
    int beg = offs[n], end = offs[n + 1];
    float s0 = 0.f, s1 = 0.f, s2 = 0.f, s3 = 0.f;
    int i = beg;
    for (; i + 4 <= end; i += 4) {
        s0 += bf2f(msg[(long)(i + 0) * 64 + lane]);
        s1 += bf2f(msg[(long)(i + 1) * 64 + lane]);
        s2 += bf2f(msg[(long)(i + 2) * 64 + lane]);
        s3 += bf2f(msg[(long)(i + 3) * 64 + lane]);
    }
    for (; i < end; ++i) s0 += bf2f(msg[(long)i * 64 + lane]);
    out[(long)n * 64 + lane] = s0 + s1 + s2 + s3;
}

extern "C" void kernel_launch(void* const* d_in, const int* in_sizes, int n_in,
                              void* d_out, int out_size, void* d_ws, size_t ws_size,
                              hipStream_t stream) {
    const float* rbf    = (const float*)d_in[0];
    const float* edge_f = (const float*)d_in[1];
    const float* node   = (const float*)d_in[2];
    const float* W1     = (const float*)d_in[3];
    const float* b1     = (const float*)d_in[4];
    const float* W2     = (const float*)d_in[5];
    const float* b2     = (const float*)d_in[6];
    const float* W3     = (const float*)d_in[7];
    const float* b3     = (const float*)d_in[8];
    const int*   src    = (const int*)d_in[9];
    const int*   dst    = (const int*)d_in[10];
    float* out = (float*)d_out;
    char* ws = (char*)d_ws;

    const int E = in_sizes[9];               // 800000 (divisible by 64)
    const int N = in_sizes[2] / 64;          // 50000
    const int NB = (N + 255) / 256;          // scan blocks

    // ws layout
    size_t off = 32768;                      // weights: 16384 ushort
    size_t counts_off = off; off += (size_t)N * 4;
    size_t cursor_off = off; off += (size_t)N * 4;
    size_t offs_off   = off; off += ((size_t)N + 1) * 4;
    off = (off + 255) & ~(size_t)255;
    size_t bsum_off = off; off += (size_t)NB * 4;
    off = (off + 255) & ~(size_t)255;
    size_t msg_off = off; off += (size_t)E * 64 * 2;
    const bool use_csr = (NB <= 256) && (ws_size >= off);

    unsigned short* wsw   = (unsigned short*)(ws);
    int* counts           = (int*)(ws + counts_off);
    int* cursor           = (int*)(ws + cursor_off);
    int* offs             = (int*)(ws + offs_off);
    int* bsum             = (int*)(ws + bsum_off);
    unsigned short* msg   = (unsigned short*)(ws + msg_off);

    prep_weights<<<1, 256, 0, stream>>>(W1, b1, W2, W3, wsw);

    if (use_csr) {
        hipMemsetAsync(counts, 0, (size_t)N * 4, stream);
        k_hist<<<(E + 255) / 256, 256, 0, stream>>>(dst, counts, E);
        k_bsum<<<NB, 256, 0, stream>>>(counts, bsum, N);
        k_scan_bsum<<<1, 256, 0, stream>>>(bsum, offs, NB, N, E);
        k_scan_final<<<NB, 256, 0, stream>>>(counts, bsum, offs, cursor, N);
        veconv_main<true><<<E / 64, 256, 0, stream>>>(rbf, edge_f, node, b2, b3, src, dst,
                                                      wsw, out, msg, cursor);
        k_segsum<<<(N + 3) / 4, 256, 0, stream>>>(msg, offs, out, N);
    } else {
        hipMemsetAsync(out, 0, (size_t)out_size * sizeof(float), stream);
        veconv_main<false><<<E / 64, 256, 0, stream>>>(rbf, edge_f, node, b2, b3, src, dst,
                                                       wsw, out, msg, cursor);
    }
}

// Round 5
// 218.262 us; speedup vs baseline: 1.7407x; 1.7407x over previous
//
#include <hip/hip_runtime.h>

// VEConv: E=800000, N=50000, RBF=100, D=64. E % 64 == 0.
// Round 5: latency attack. Round-4 counters showed ~56k stall cycles/wave
// (~60 serialized memory round-trips). Fixes:
//   (1) weights staged once per block into LDS in dump-fragment order
//       (frag f, lane, 16B contiguous -> conflict-minimal ds_read_b128),
//   (2) all global loads burst-issued at kernel top (named registers),
//   (3) back to the single-kernel f32-atomic epilogue (round-4 measured the
//       51.2M atomics at only ~13 us; CSR build+segsum cost +50 us).
#define RBF_DIM 100

typedef __attribute__((ext_vector_type(8))) short bf16x8;
typedef __attribute__((ext_vector_type(4))) float f32x4;

__device__ __forceinline__ unsigned short f2bf(float f) {
    union { float f; unsigned int u; } v; v.f = f;
    unsigned int r = (v.u + 0x7FFFu + ((v.u >> 16) & 1u)) >> 16;
    return (unsigned short)r;
}
__device__ __forceinline__ bf16x8 cvt8(f32x4 a, f32x4 b) {
    bf16x8 r;
    r[0] = (short)f2bf(a[0]); r[1] = (short)f2bf(a[1]);
    r[2] = (short)f2bf(a[2]); r[3] = (short)f2bf(a[3]);
    r[4] = (short)f2bf(b[0]); r[5] = (short)f2bf(b[1]);
    r[6] = (short)f2bf(b[2]); r[7] = (short)f2bf(b[3]);
    return r;
}

// ---- pre-kernel: weights as bf16 MFMA fragments, dump order ----
// ws ushort layout: 32 frags x 64 lanes x 8 elems (16 KB W1 + 8 KB W2 + 8 KB W3)
//   f in [0,16):  W1T frag (t4=f>>2, ks=f&3), k=32ks+8g+j (k=100 -> b1, >100 -> 0)
//   f in [16,24): W2T frag (t4=(f-16)>>1, ks=(f-16)&1)
//   f in [24,32): W3T frag (t4=(f-24)>>1, ks=(f-24)&1)
__global__ void prep_weights(const float* __restrict__ W1, const float* __restrict__ b1,
                             const float* __restrict__ W2, const float* __restrict__ W3,
                             unsigned short* __restrict__ ws) {
    for (int e = threadIdx.x; e < 32 * 64 * 8; e += 256) {
        int f = e >> 9;
        int lane = (e >> 3) & 63;
        int j = e & 7;
        int l15 = lane & 15, g = lane >> 4;
        float v;
        if (f < 16) {
            int t4 = f >> 2, ks = f & 3;
            int k = 32 * ks + 8 * g + j, o = 16 * t4 + l15;
            v = (k < RBF_DIM) ? W1[k * 64 + o] : ((k == RBF_DIM) ? b1[o] : 0.0f);
        } else if (f < 24) {
            int q = f - 16, t4 = q >> 1, ks = q & 1;
            int k = 32 * ks + 8 * g + j, o = 16 * t4 + l15;
            v = W2[k * 64 + o];
        } else {
            int q = f - 24, t4 = q >> 1, ks = q & 1;
            int k = 32 * ks + 8 * g + j, o = 16 * t4 + l15;
            v = W3[k * 64 + o];
        }
        ws[e] = f2bf(v);
    }
}

// ---- main fused kernel: 64 edges/block, 4 waves x 16 edges ----
__global__ __launch_bounds__(256, 4)
void veconv_main(const float* __restrict__ rbf, const float* __restrict__ edge_f,
                 const float* __restrict__ node,
                 const float* __restrict__ b2, const float* __restrict__ b3,
                 const int* __restrict__ src, const int* __restrict__ dst,
                 const unsigned short* __restrict__ wsw,
                 float* __restrict__ out) {
    __shared__ unsigned short wlds[32 * 512];     // 32 KB fragment-ordered weights
    __shared__ unsigned short sp_lds[4 * 16 * 64]; // 8 KB softplus transpose (per-wave)

    const int tid = threadIdx.x;
    const int lane = tid & 63, wid = tid >> 6;
    const int l15 = lane & 15, g = lane >> 4;
    const int ew0 = blockIdx.x * 64 + wid * 16;
    const int eg = ew0 + l15;
    const int swz = (l15 & 7) << 3;

    // ---- burst-issue ALL long-latency global loads as named registers ----
    const float* rrow = rbf + (long)eg * RBF_DIM;
    const f32x4 ra0 = *(const f32x4*)(rrow + 8 * g);
    const f32x4 ra1 = *(const f32x4*)(rrow + 8 * g + 4);
    const f32x4 rb0 = *(const f32x4*)(rrow + 32 + 8 * g);
    const f32x4 rb1 = *(const f32x4*)(rrow + 32 + 8 * g + 4);
    const f32x4 rc0 = *(const f32x4*)(rrow + 64 + 8 * g);
    const f32x4 rc1 = *(const f32x4*)(rrow + 64 + 8 * g + 4);
    f32x4 rt = (f32x4){0.f, 0.f, 0.f, 0.f};
    if (g == 0) rt = *(const f32x4*)(rrow + 96);
    const float* erow = edge_f + (long)eg * 64;
    const f32x4 ea0 = *(const f32x4*)(erow + 8 * g);
    const f32x4 ea1 = *(const f32x4*)(erow + 8 * g + 4);
    const f32x4 eb0 = *(const f32x4*)(erow + 32 + 8 * g);
    const f32x4 eb1 = *(const f32x4*)(erow + 32 + 8 * g + 4);
    const int4 s4 = *(const int4*)(src + ew0 + 4 * g);
    const int4 d4 = *(const int4*)(dst + ew0 + 4 * g);
    float b2v[4], b3v[4];
    for (int t4 = 0; t4 < 4; ++t4) { b2v[t4] = b2[16 * t4 + l15]; b3v[t4] = b3[16 * t4 + l15]; }

    // ---- stage weights to LDS (one-time, cooperative, coalesced) ----
    {
        const uint4* wg = (const uint4*)wsw;
        uint4* wl = (uint4*)wlds;
#pragma unroll
        for (int i = 0; i < 8; ++i) wl[tid + 256 * i] = wg[tid + 256 * i];
    }

    // ---- node gathers (depend only on s4) ----
    const int sv[4] = {s4.x, s4.y, s4.z, s4.w};
    const int dv[4] = {d4.x, d4.y, d4.z, d4.w};
    float nd[4][4];
    for (int r = 0; r < 4; ++r)
        for (int t4 = 0; t4 < 4; ++t4)
            nd[r][t4] = node[(long)sv[r] * 64 + 16 * t4 + l15];

    __syncthreads();   // weights visible to all waves

    const bf16x8* frg = (const bf16x8*)wlds;  // frag f, lane: frg[f*64 + lane]

    // ---- GEMM1: D1[d][e] = W1T @ rbf^T ----
    bf16x8 bfk[4];
    bfk[0] = cvt8(ra0, ra1);
    bfk[1] = cvt8(rb0, rb1);
    bfk[2] = cvt8(rc0, rc1);
    {
        bf16x8 bt = (bf16x8){0, 0, 0, 0, 0, 0, 0, 0};
        if (g == 0) {
            bt[0] = (short)f2bf(rt[0]); bt[1] = (short)f2bf(rt[1]);
            bt[2] = (short)f2bf(rt[2]); bt[3] = (short)f2bf(rt[3]);
            bt[4] = (short)0x3F80;   // k=100 bias-1.0 column
        }
        bfk[3] = bt;
    }
    f32x4 acc1[4];
    for (int t4 = 0; t4 < 4; ++t4) acc1[t4] = (f32x4){0.f, 0.f, 0.f, 0.f};
    for (int ks = 0; ks < 4; ++ks)
        for (int t4 = 0; t4 < 4; ++t4)
            acc1[t4] = __builtin_amdgcn_mfma_f32_16x16x32_bf16(frg[(t4 * 4 + ks) * 64 + lane],
                                                               bfk[ks], acc1[t4], 0, 0, 0);

    // ---- softplus(beta=0.5, thr=14) -> sp_lds (intra-wave region, no barrier) ----
    // D1 layout: lane (g,l15) holds col e=l15, rows d = 16*t4 + 4*g + r
    for (int t4 = 0; t4 < 4; ++t4) {
        float spv[4];
        for (int r = 0; r < 4; ++r) {
            float x = acc1[t4][r];
            float bx = 0.5f * x;
            float s = 2.0f * __logf(1.0f + __expf(bx));
            spv[r] = (bx > 14.0f) ? x : s;
        }
        unsigned int p0 = (unsigned int)f2bf(spv[0]) | ((unsigned int)f2bf(spv[1]) << 16);
        unsigned int p1 = (unsigned int)f2bf(spv[2]) | ((unsigned int)f2bf(spv[3]) << 16);
        int el = (wid * 16 + l15) * 64 + ((16 * t4 + 4 * g) ^ swz);
        *(uint2*)&sp_lds[el] = make_uint2(p0, p1);
    }

    // ---- GEMM2/3 swapped operands: D[e][d] edge-major ----
    bf16x8 aef[2];
    aef[0] = cvt8(ea0, ea1);
    aef[1] = cvt8(eb0, eb1);
    f32x4 acc2[4], acc3[4];
    for (int t4 = 0; t4 < 4; ++t4) {
        acc2[t4] = (f32x4){0.f, 0.f, 0.f, 0.f};
        acc3[t4] = (f32x4){0.f, 0.f, 0.f, 0.f};
    }
    for (int ks = 0; ks < 2; ++ks) {
        bf16x8 asp = *(const bf16x8*)&sp_lds[(wid * 16 + l15) * 64 + ((32 * ks + 8 * g) ^ swz)];
        for (int t4 = 0; t4 < 4; ++t4) {
            acc2[t4] = __builtin_amdgcn_mfma_f32_16x16x32_bf16(asp,
                          frg[(16 + t4 * 2 + ks) * 64 + lane], acc2[t4], 0, 0, 0);
            acc3[t4] = __builtin_amdgcn_mfma_f32_16x16x32_bf16(aef[ks],
                          frg[(24 + t4 * 2 + ks) * 64 + lane], acc3[t4], 0, 0, 0);
        }
    }
    // acc2/acc3: lane (g,l15) holds edge 4g+r, dim 16*t4+l15

    // ---- epilogue: contiguous-dim atomic scatter straight from accumulators ----
    for (int r = 0; r < 4; ++r) {
        float* orow = out + (long)dv[r] * 64 + l15;
        for (int t4 = 0; t4 < 4; ++t4) {
            float msg = nd[r][t4] * (acc2[t4][r] + b2v[t4]) + (acc3[t4][r] + b3v[t4]);
            atomicAdd(&orow[16 * t4], msg);
        }
    }
}

extern "C" void kernel_launch(void* const* d_in, const int* in_sizes, int n_in,
                              void* d_out, int out_size, void* d_ws, size_t ws_size,
                              hipStream_t stream) {
    const float* rbf    = (const float*)d_in[0];
    const float* edge_f = (const float*)d_in[1];
    const float* node   = (const float*)d_in[2];
    const float* W1     = (const float*)d_in[3];
    const float* b1     = (const float*)d_in[4];
    const float* W2     = (const float*)d_in[5];
    const float* b2     = (const float*)d_in[6];
    const float* W3     = (const float*)d_in[7];
    const float* b3     = (const float*)d_in[8];
    const int*   src    = (const int*)d_in[9];
    const int*   dst    = (const int*)d_in[10];
    float* out = (float*)d_out;
    unsigned short* ws = (unsigned short*)d_ws;

    const int E = in_sizes[9];              // 800000, divisible by 64

    hipMemsetAsync(d_out, 0, (size_t)out_size * sizeof(float), stream);
    prep_weights<<<1, 256, 0, stream>>>(W1, b1, W2, W3, ws);
    veconv_main<<<E / 64, 256, 0, stream>>>(rbf, edge_f, node, b2, b3, src, dst, ws, out);
}